// Round 1
// 1518.855 us; speedup vs baseline: 1.1620x; 1.1620x over previous
//
#include <hip/hip_runtime.h>

#define DEV __device__ __forceinline__

typedef __bf16 bf16x8 __attribute__((ext_vector_type(8)));
typedef unsigned short ushort8v __attribute__((ext_vector_type(8)));
typedef float floatx4 __attribute__((ext_vector_type(4)));

DEV unsigned short f2bf(float f) {
  unsigned int u = __float_as_uint(f);
  u += 0x7fffu + ((u >> 16) & 1u);   // RNE
  return (unsigned short)(u >> 16);
}

// ---------------- cast fp32 -> bf16 (vectorized) ----------------
__global__ __launch_bounds__(256) void cast_bf16_kernel(
    const float* __restrict__ in, unsigned short* __restrict__ out, int n4) {
  int i = blockIdx.x * 256 + threadIdx.x;
  if (i >= n4) return;
  float4 v = ((const float4*)in)[i];
  ushort4 o;
  o.x = f2bf(v.x); o.y = f2bf(v.y); o.z = f2bf(v.z); o.w = f2bf(v.w);
  ((ushort4*)out)[i] = o;
}

// ---------------- tiled transpose + cast: out[C][R] = bf16(in[R][C]) ----------------
__global__ __launch_bounds__(256) void transpose_cast_kernel(
    const float* __restrict__ in, unsigned short* __restrict__ out, int R, int C) {
  __shared__ float tile[32][33];
  int c0 = blockIdx.x * 32, r0 = blockIdx.y * 32;
  int tx = threadIdx.x, ty = threadIdx.y;
#pragma unroll
  for (int j = 0; j < 32; j += 8)
    tile[ty + j][tx] = in[(long)(r0 + ty + j) * C + (c0 + tx)];
  __syncthreads();
#pragma unroll
  for (int j = 0; j < 32; j += 8)
    out[(long)(c0 + ty + j) * R + (r0 + tx)] = f2bf(tile[tx][ty + j]);
}

// ---------------- generic NT GEMM: C[M,N] = A[M,K] * B[N,K]^T, bf16 MFMA ----------------
// Per-wave 64x64 (4x4 tiles of 16x16x32), block = WM x WN waves.
enum GemmMode { M_QPROJ = 0, M_KPROJ, M_VPROJ, M_SCORES, M_CTX, M_OPROJ, M_FFN1, M_FFN2 };

template <int MODE, int WM, int WN>
__global__ __launch_bounds__(WM * WN * 64)
void gemm_nt(const void* __restrict__ Ap, const unsigned short* __restrict__ Bp,
             const float* __restrict__ bias, void* __restrict__ Cp,
             const float* __restrict__ mask, int K, int ldA, int ldB,
             long zsA, long zsB) {
  constexpr int BM = WM * 64, BN = WN * 64, BK = 32, LDK = 40;  // LDK pad: 80B rows, 16B aligned
  constexpr int NT = WM * WN * 64;
  constexpr bool A_F32 = (MODE == M_CTX);
  __shared__ unsigned short As[BM * LDK];
  __shared__ unsigned short Bs[BN * LDK];

  const int tid = threadIdx.x;
  const int z = blockIdx.z;
  const long bm = (long)blockIdx.y * BM;
  const long bn = (long)blockIdx.x * BN;

  const float* Af = nullptr;
  const unsigned short* Ab = nullptr;
  if constexpr (A_F32) Af = (const float*)Ap + (long)z * zsA + bm * ldA;
  else                 Ab = (const unsigned short*)Ap + (long)z * zsA + bm * ldA;
  const unsigned short* B = Bp + (long)z * zsB + bn * ldB;

  const int wave = tid >> 6, lane = tid & 63;
  const int wn = wave % WN, wm = wave / WN;
  const int lr = lane & 15, kq = lane >> 4;  // fragment row/col, k-quad

  floatx4 acc[4][4];
#pragma unroll
  for (int mt = 0; mt < 4; ++mt)
#pragma unroll
    for (int nt = 0; nt < 4; ++nt) acc[mt][nt] = floatx4{0.f, 0.f, 0.f, 0.f};

  for (int k0 = 0; k0 < K; k0 += BK) {
    __syncthreads();
    // stage A tile [BM][BK]
#pragma unroll
    for (int c = tid; c < BM * 4; c += NT) {
      int r = c >> 2, kc = (c & 3) << 3;
      unsigned short* dst = &As[r * LDK + kc];
      if constexpr (A_F32) {
        const float* src = Af + (long)r * ldA + k0 + kc;
        float4 v0 = *(const float4*)src;
        float4 v1 = *(const float4*)(src + 4);
        ushort4 a{f2bf(v0.x), f2bf(v0.y), f2bf(v0.z), f2bf(v0.w)};
        ushort4 b{f2bf(v1.x), f2bf(v1.y), f2bf(v1.z), f2bf(v1.w)};
        *(ushort4*)dst = a;
        *(ushort4*)(dst + 4) = b;
      } else {
        *(ushort8v*)dst = *(const ushort8v*)(Ab + (long)r * ldA + k0 + kc);
      }
    }
    // stage B tile [BN][BK]
#pragma unroll
    for (int c = tid; c < BN * 4; c += NT) {
      int r = c >> 2, kc = (c & 3) << 3;
      *(ushort8v*)&Bs[r * LDK + kc] = *(const ushort8v*)(B + (long)r * ldB + k0 + kc);
    }
    __syncthreads();

    bf16x8 af[4], bfr[4];
#pragma unroll
    for (int mt = 0; mt < 4; ++mt)
      af[mt] = *(const bf16x8*)&As[(wm * 64 + mt * 16 + lr) * LDK + kq * 8];
#pragma unroll
    for (int nt = 0; nt < 4; ++nt)
      bfr[nt] = *(const bf16x8*)&Bs[(wn * 64 + nt * 16 + lr) * LDK + kq * 8];
#pragma unroll
    for (int mt = 0; mt < 4; ++mt)
#pragma unroll
      for (int nt = 0; nt < 4; ++nt)
        acc[mt][nt] = __builtin_amdgcn_mfma_f32_16x16x32_bf16(af[mt], bfr[nt], acc[mt][nt], 0, 0, 0);
  }

  // epilogue: C/D layout col = lane&15 (lr), row = (lane>>4)*4 + i (kq)
#pragma unroll
  for (int mt = 0; mt < 4; ++mt) {
#pragma unroll
    for (int nt = 0; nt < 4; ++nt) {
#pragma unroll
      for (int i = 0; i < 4; ++i) {
        long gm = bm + wm * 64 + mt * 16 + kq * 4 + i;
        long gn = bn + wn * 64 + nt * 16 + lr;
        float v = acc[mt][nt][i];
        if constexpr (MODE == M_QPROJ || MODE == M_KPROJ) {
          v += bias[gn];
          if constexpr (MODE == M_QPROJ) v *= 0.125f;  // fold 1/sqrt(HD)
          long b = gm >> 10, s = gm & 1023, h = gn >> 6, hd = gn & 63;
          ((unsigned short*)Cp)[((b * 16 + h) << 16) + (s << 6) + hd] = f2bf(v);
        } else if constexpr (MODE == M_VPROJ) {
          v += bias[gn];
          long b = gm >> 10, s = gm & 1023, h = gn >> 6, hd = gn & 63;
          ((unsigned short*)Cp)[((b * 16 + h) << 16) + (hd << 10) + s] = f2bf(v);  // V^T layout
        } else if constexpr (MODE == M_SCORES) {
          v += (1.0f - mask[(long)(z >> 4) * 1024 + gn]) * -10000.0f;
          ((float*)Cp)[(long)z * 1048576 + gm * 1024 + gn] = v;
        } else if constexpr (MODE == M_CTX) {
          long b = z >> 4, h = z & 15;
          ((unsigned short*)Cp)[((b * 1024 + gm) << 10) + (h << 6) + gn] = f2bf(v);
        } else if constexpr (MODE == M_OPROJ || MODE == M_FFN2) {
          ((float*)Cp)[gm * 1024 + gn] = v + bias[gn];
        } else if constexpr (MODE == M_FFN1) {
          ((unsigned short*)Cp)[gm * 4096 + gn] = f2bf(fmaxf(v + bias[gn], 0.f));
        }
      }
    }
  }
}

// ---------------- fused attention: scores + softmax + probs-out + P·V ----------------
// One block per (b,h, q-block of 128 rows). 256 threads = 4 waves, wm = wave>>1 (q half),
// wn = wave&1 (col half for QK^T, hd half for PV).
// Pass 1: online (m,l) per row over all 1024 cols (scores recomputable: K=64).
// Pass 2: recompute scores, write normalized fp32 probs to d_out, bf16 P -> LDS
// (XOR-swizzled so the acc->A-fragment transpose is bank-spread), accumulate P·V.
__global__ __launch_bounds__(256) void attn_fused_kernel(
    const unsigned short* __restrict__ Qh, const unsigned short* __restrict__ Kh,
    const unsigned short* __restrict__ VhT, const float* __restrict__ mask,
    float* __restrict__ probs, unsigned short* __restrict__ Ctx) {
  constexpr int LDK = 72;   // 64 + 8 pad ushorts (144B rows, 16B aligned)
  constexpr int LDP = 136;  // 128 + 8 pad ushorts (272B rows, 16B aligned)
  __shared__ unsigned short Klds[128 * LDK];   // 18.0 KB (also reused for m/l merge)
  __shared__ unsigned short Ps[128 * LDP];     // 34.0 KB

  // XCD-chunked swizzle: consecutive blockIdx round-robin XCDs; give each XCD a
  // contiguous chunk of (b,h) so its K/V working set stays L2-resident.
  int bid = blockIdx.x;
  int orig = (bid & 7) * 128 + (bid >> 3);
  const int z = orig >> 3, qb = orig & 7;

  const long zoff = (long)z << 16;
  const unsigned short* Qp = Qh + zoff + ((long)qb << 13);
  const unsigned short* Kp = Kh + zoff;
  const unsigned short* Vp = VhT + zoff;
  const float* mrow = mask + (long)(z >> 4) * 1024;
  float* prow = probs + ((long)z << 20) + ((long)qb << 17);

  const int tid = threadIdx.x;
  const int wave = tid >> 6, lane = tid & 63;
  const int wm = wave >> 1, wn = wave & 1;
  const int lr = lane & 15, kq = lane >> 4;

  // Q fragments held in registers for the whole kernel: rows wm*64+mt*16+lr, k = ks*32+kq*8
  bf16x8 qf[4][2];
#pragma unroll
  for (int mt = 0; mt < 4; ++mt)
#pragma unroll
    for (int ks = 0; ks < 2; ++ks)
      qf[mt][ks] = *(const bf16x8*)(Qp + (wm * 64 + mt * 16 + lr) * 64 + ks * 32 + kq * 8);

  float m_run[4][4], l_run[4][4];
#pragma unroll
  for (int mt = 0; mt < 4; ++mt)
#pragma unroll
    for (int i = 0; i < 4; ++i) { m_run[mt][i] = -3.0e38f; l_run[mt][i] = 0.f; }

  // ---- pass 1: per-row running max / exp-sum over this wave's column half ----
  for (int c = 0; c < 8; ++c) {
    __syncthreads();
#pragma unroll
    for (int cc = tid; cc < 1024; cc += 256) {
      int r = cc >> 3, kc = (cc & 7) << 3;
      *(ushort8v*)&Klds[r * LDK + kc] = *(const ushort8v*)(Kp + ((c << 7) + r) * 64 + kc);
    }
    __syncthreads();
    bf16x8 kf[2][4];
#pragma unroll
    for (int ks = 0; ks < 2; ++ks)
#pragma unroll
      for (int nt = 0; nt < 4; ++nt)
        kf[ks][nt] = *(const bf16x8*)&Klds[(wn * 64 + nt * 16 + lr) * LDK + ks * 32 + kq * 8];
    float mk[4];
#pragma unroll
    for (int nt = 0; nt < 4; ++nt)
      mk[nt] = (1.0f - mrow[(c << 7) + wn * 64 + nt * 16 + lr]) * -10000.0f;
#pragma unroll
    for (int mt = 0; mt < 4; ++mt) {
      floatx4 a[4];
#pragma unroll
      for (int nt = 0; nt < 4; ++nt) a[nt] = floatx4{0.f, 0.f, 0.f, 0.f};
#pragma unroll
      for (int ks = 0; ks < 2; ++ks)
#pragma unroll
        for (int nt = 0; nt < 4; ++nt)
          a[nt] = __builtin_amdgcn_mfma_f32_16x16x32_bf16(qf[mt][ks], kf[ks][nt], a[nt], 0, 0, 0);
#pragma unroll
      for (int i = 0; i < 4; ++i) {
        float s0 = a[0][i] + mk[0], s1 = a[1][i] + mk[1];
        float s2 = a[2][i] + mk[2], s3 = a[3][i] + mk[3];
        float tm = fmaxf(fmaxf(s0, s1), fmaxf(s2, s3));
#pragma unroll
        for (int o = 1; o < 16; o <<= 1) tm = fmaxf(tm, __shfl_xor(tm, o));
        float mn = fmaxf(m_run[mt][i], tm);
        float ps = __expf(s0 - mn) + __expf(s1 - mn) + __expf(s2 - mn) + __expf(s3 - mn);
#pragma unroll
        for (int o = 1; o < 16; o <<= 1) ps += __shfl_xor(ps, o);
        l_run[mt][i] = l_run[mt][i] * __expf(m_run[mt][i] - mn) + ps;
        m_run[mt][i] = mn;
      }
    }
  }

  // ---- merge (m,l) across the two wn column-half waves via LDS ----
  __syncthreads();
  float* mred = (float*)Klds;      // [2][128]
  float* lred = mred + 256;
  if (lr == 0) {
#pragma unroll
    for (int mt = 0; mt < 4; ++mt)
#pragma unroll
      for (int i = 0; i < 4; ++i) {
        int r = wm * 64 + mt * 16 + kq * 4 + i;
        mred[wn * 128 + r] = m_run[mt][i];
        lred[wn * 128 + r] = l_run[mt][i];
      }
  }
  __syncthreads();
  float rl[4][4];
#pragma unroll
  for (int mt = 0; mt < 4; ++mt)
#pragma unroll
    for (int i = 0; i < 4; ++i) {
      int r = wm * 64 + mt * 16 + kq * 4 + i;
      float m0 = mred[r], m1 = mred[128 + r];
      float l0 = lred[r], l1 = lred[128 + r];
      float mm = fmaxf(m0, m1);
      float ll = l0 * __expf(m0 - mm) + l1 * __expf(m1 - mm);
      m_run[mt][i] = mm;
      rl[mt][i] = 1.0f / ll;
    }

  // ---- pass 2: probs out (fp32), P -> LDS (bf16, swizzled), P·V accumulate ----
  floatx4 cacc[4][2];
#pragma unroll
  for (int mt = 0; mt < 4; ++mt)
#pragma unroll
    for (int n2 = 0; n2 < 2; ++n2) cacc[mt][n2] = floatx4{0.f, 0.f, 0.f, 0.f};

  for (int c = 0; c < 8; ++c) {
    __syncthreads();  // prev PV P-reads + prev score K-reads done; safe to restage
#pragma unroll
    for (int cc = tid; cc < 1024; cc += 256) {
      int r = cc >> 3, kc = (cc & 7) << 3;
      *(ushort8v*)&Klds[r * LDK + kc] = *(const ushort8v*)(Kp + ((c << 7) + r) * 64 + kc);
    }
    __syncthreads();
    bf16x8 kf[2][4];
#pragma unroll
    for (int ks = 0; ks < 2; ++ks)
#pragma unroll
      for (int nt = 0; nt < 4; ++nt)
        kf[ks][nt] = *(const bf16x8*)&Klds[(wn * 64 + nt * 16 + lr) * LDK + ks * 32 + kq * 8];
    float mk[4];
#pragma unroll
    for (int nt = 0; nt < 4; ++nt)
      mk[nt] = (1.0f - mrow[(c << 7) + wn * 64 + nt * 16 + lr]) * -10000.0f;
#pragma unroll
    for (int mt = 0; mt < 4; ++mt) {
      floatx4 a[4];
#pragma unroll
      for (int nt = 0; nt < 4; ++nt) a[nt] = floatx4{0.f, 0.f, 0.f, 0.f};
#pragma unroll
      for (int ks = 0; ks < 2; ++ks)
#pragma unroll
        for (int nt = 0; nt < 4; ++nt)
          a[nt] = __builtin_amdgcn_mfma_f32_16x16x32_bf16(qf[mt][ks], kf[ks][nt], a[nt], 0, 0, 0);
#pragma unroll
      for (int nt = 0; nt < 4; ++nt) {
#pragma unroll
        for (int i = 0; i < 4; ++i) {
          float p = __expf(a[nt][i] + mk[nt] - m_run[mt][i]) * rl[mt][i];
          int row = wm * 64 + mt * 16 + kq * 4 + i;
          int col = wn * 64 + nt * 16 + lr;
          prow[(long)row * 1024 + (c << 7) + col] = p;
          // swizzle key = (row>>2)&3 == kq here; spreads the 4 kq groups across banks
          Ps[row * LDP + (col ^ (kq << 4))] = f2bf(p);
        }
      }
    }
    __syncthreads();  // Ps tile complete
#pragma unroll
    for (int k2 = 0; k2 < 4; ++k2) {
      bf16x8 pa[4], vb[2];
#pragma unroll
      for (int mt = 0; mt < 4; ++mt) {
        int row = wm * 64 + mt * 16 + lr;  // (row>>2)&3 == lr>>2
        pa[mt] = *(const bf16x8*)&Ps[row * LDP + ((k2 * 32 + kq * 8) ^ ((lr >> 2) << 4))];
      }
#pragma unroll
      for (int n2 = 0; n2 < 2; ++n2)
        vb[n2] = *(const bf16x8*)(Vp + (wn * 32 + n2 * 16 + lr) * 1024 + (c << 7) + k2 * 32 + kq * 8);
#pragma unroll
      for (int mt = 0; mt < 4; ++mt)
#pragma unroll
        for (int n2 = 0; n2 < 2; ++n2)
          cacc[mt][n2] = __builtin_amdgcn_mfma_f32_16x16x32_bf16(pa[mt], vb[n2], cacc[mt][n2], 0, 0, 0);
    }
  }

  // ---- context epilogue: Ctx[b][s][h*64+hd] bf16 (same layout as old M_CTX) ----
  const int b = z >> 4, h = z & 15;
#pragma unroll
  for (int mt = 0; mt < 4; ++mt)
#pragma unroll
    for (int n2 = 0; n2 < 2; ++n2)
#pragma unroll
      for (int i = 0; i < 4; ++i) {
        long srow = (long)b * 1024 + qb * 128 + wm * 64 + mt * 16 + kq * 4 + i;
        int hd = wn * 32 + n2 * 16 + lr;
        Ctx[(srow << 10) + (h << 6) + hd] = f2bf(cacc[mt][n2][i]);
      }
}

// ---------------- LayerNorm helpers ----------------
DEV void block_reduce2(float& s, float& s2, float* buf) {
  int wid = threadIdx.x >> 6, lane = threadIdx.x & 63;
#pragma unroll
  for (int o = 32; o > 0; o >>= 1) { s += __shfl_down(s, o); s2 += __shfl_down(s2, o); }
  if (lane == 0) { buf[wid] = s; buf[4 + wid] = s2; }
  __syncthreads();
  s = buf[0] + buf[1] + buf[2] + buf[3];
  s2 = buf[4] + buf[5] + buf[6] + buf[7];
  __syncthreads();
}

// y1 = LN(proj + query; g1,b1,1e-8); y2 = LN(query + y1; g2,b2,1e-6) -> fp32 + bf16
__global__ __launch_bounds__(256)
void ln_mha_kernel(const float* __restrict__ proj, const float* __restrict__ query,
                   const float* __restrict__ g1, const float* __restrict__ b1,
                   const float* __restrict__ g2, const float* __restrict__ b2,
                   float* __restrict__ attn_out, unsigned short* __restrict__ attn_out_bf) {
  __shared__ float buf[8];
  long row = blockIdx.x;
  int t = threadIdx.x;
  float4 a = ((const float4*)(proj + (row << 10)))[t];
  float4 q = ((const float4*)(query + (row << 10)))[t];
  float4 x{a.x + q.x, a.y + q.y, a.z + q.z, a.w + q.w};
  float s = x.x + x.y + x.z + x.w;
  float s2 = x.x * x.x + x.y * x.y + x.z * x.z + x.w * x.w;
  block_reduce2(s, s2, buf);
  float mu = s * (1.f / 1024.f);
  float inv = rsqrtf(fmaxf(s2 * (1.f / 1024.f) - mu * mu, 0.f) + 1e-8f);
  float4 g = ((const float4*)g1)[t], bb = ((const float4*)b1)[t];
  float4 y{(x.x - mu) * inv * g.x + bb.x, (x.y - mu) * inv * g.y + bb.y,
           (x.z - mu) * inv * g.z + bb.z, (x.w - mu) * inv * g.w + bb.w};
  float4 x2{q.x + y.x, q.y + y.y, q.z + y.z, q.w + y.w};
  s = x2.x + x2.y + x2.z + x2.w;
  s2 = x2.x * x2.x + x2.y * x2.y + x2.z * x2.z + x2.w * x2.w;
  block_reduce2(s, s2, buf);
  mu = s * (1.f / 1024.f);
  inv = rsqrtf(fmaxf(s2 * (1.f / 1024.f) - mu * mu, 0.f) + 1e-6f);
  g = ((const float4*)g2)[t]; bb = ((const float4*)b2)[t];
  float4 o{(x2.x - mu) * inv * g.x + bb.x, (x2.y - mu) * inv * g.y + bb.y,
           (x2.z - mu) * inv * g.z + bb.z, (x2.w - mu) * inv * g.w + bb.w};
  ((float4*)(attn_out + (row << 10)))[t] = o;
  ushort4 ob{f2bf(o.x), f2bf(o.y), f2bf(o.z), f2bf(o.w)};
  ((ushort4*)(attn_out_bf + (row << 10)))[t] = ob;
}

// out = LN(ffn + res; g,b,1e-6) -> d_out fp32
__global__ __launch_bounds__(256)
void ln_final_kernel(const float* __restrict__ ffn, const float* __restrict__ res,
                     const float* __restrict__ g1, const float* __restrict__ b1,
                     float* __restrict__ out) {
  __shared__ float buf[8];
  long row = blockIdx.x;
  int t = threadIdx.x;
  float4 a = ((const float4*)(ffn + (row << 10)))[t];
  float4 q = ((const float4*)(res + (row << 10)))[t];
  float4 x{a.x + q.x, a.y + q.y, a.z + q.z, a.w + q.w};
  float s = x.x + x.y + x.z + x.w;
  float s2 = x.x * x.x + x.y * x.y + x.z * x.z + x.w * x.w;
  block_reduce2(s, s2, buf);
  float mu = s * (1.f / 1024.f);
  float inv = rsqrtf(fmaxf(s2 * (1.f / 1024.f) - mu * mu, 0.f) + 1e-6f);
  float4 g = ((const float4*)g1)[t], bb = ((const float4*)b1)[t];
  float4 o{(x.x - mu) * inv * g.x + bb.x, (x.y - mu) * inv * g.y + bb.y,
           (x.z - mu) * inv * g.z + bb.z, (x.w - mu) * inv * g.w + bb.w};
  ((float4*)(out + (row << 10)))[t] = o;
}

extern "C" void kernel_launch(void* const* d_in, const int* in_sizes, int n_in,
                              void* d_out, int out_size, void* d_ws, size_t ws_size,
                              hipStream_t stream) {
  const float* query = (const float*)d_in[0];
  const float* key   = (const float*)d_in[1];
  const float* value = (const float*)d_in[2];
  const float* mask  = (const float*)d_in[3];
  const float* wq = (const float*)d_in[4];  const float* bq = (const float*)d_in[5];
  const float* wk = (const float*)d_in[6];  const float* bk = (const float*)d_in[7];
  const float* wv = (const float*)d_in[8];  const float* bv = (const float*)d_in[9];
  const float* wo = (const float*)d_in[10]; const float* bo = (const float*)d_in[11];
  const float* ln_mha_g = (const float*)d_in[12]; const float* ln_mha_b = (const float*)d_in[13];
  const float* w1 = (const float*)d_in[14]; const float* b1 = (const float*)d_in[15];
  const float* w2 = (const float*)d_in[16]; const float* b2 = (const float*)d_in[17];
  const float* ln_attn_g = (const float*)d_in[18]; const float* ln_attn_b = (const float*)d_in[19];
  const float* ln_ffn_g = (const float*)d_in[20];  const float* ln_ffn_b = (const float*)d_in[21];

  // workspace layout (elements); Hid (64MB) aliases [Xq,Xk,Xv,Qh] which are dead by FFN1
  unsigned short* Xq  = (unsigned short*)d_ws;          // 8192x1024
  unsigned short* Xk  = Xq + 8388608;
  unsigned short* Xv  = Xk + 8388608;
  unsigned short* Qh  = Xv + 8388608;                   // [B*H][S][HD]
  unsigned short* Hid = (unsigned short*)d_ws;          // 8192x4096 (alias)
  unsigned short* Kh  = Qh + 8388608;
  unsigned short* VhT = Kh + 8388608;                   // [B*H][HD][S]
  unsigned short* WqT = VhT + 8388608;                  // [N][K]
  unsigned short* WkT = WqT + 1048576;
  unsigned short* WvT = WkT + 1048576;
  unsigned short* WoT = WvT + 1048576;
  unsigned short* W1T = WoT + 1048576;                  // [4096][1024]
  unsigned short* W2T = W1T + 4194304;                  // [1024][4096]
  unsigned short* Ctx = W2T + 4194304;                  // 8192x1024 bf16
  float* tmp1    = (float*)(Ctx + 8388608);             // 8192x1024 fp32 (o-proj out, reused for ffn out)
  float* AttnOut = tmp1 + 8388608;                      // 8192x1024 fp32
  unsigned short* AttnOutBf = (unsigned short*)(AttnOut + 8388608);

  float* attnF = (float*)d_out + 8388608;               // attn_weights region [B*H][S][S]
  float* outF  = (float*)d_out;

  // 1) casts
  cast_bf16_kernel<<<8192, 256, 0, stream>>>(query, Xq, 2097152);
  cast_bf16_kernel<<<8192, 256, 0, stream>>>(key,   Xk, 2097152);
  cast_bf16_kernel<<<8192, 256, 0, stream>>>(value, Xv, 2097152);
  // 2) weight transposes -> [N][K] bf16
  transpose_cast_kernel<<<dim3(32, 32), dim3(32, 8), 0, stream>>>(wq, WqT, 1024, 1024);
  transpose_cast_kernel<<<dim3(32, 32), dim3(32, 8), 0, stream>>>(wk, WkT, 1024, 1024);
  transpose_cast_kernel<<<dim3(32, 32), dim3(32, 8), 0, stream>>>(wv, WvT, 1024, 1024);
  transpose_cast_kernel<<<dim3(32, 32), dim3(32, 8), 0, stream>>>(wo, WoT, 1024, 1024);
  transpose_cast_kernel<<<dim3(128, 32), dim3(32, 8), 0, stream>>>(w1, W1T, 1024, 4096);
  transpose_cast_kernel<<<dim3(32, 128), dim3(32, 8), 0, stream>>>(w2, W2T, 4096, 1024);
  // 3) QKV projections (head-layout epilogues; Q pre-scaled by 0.125)
  gemm_nt<M_QPROJ, 2, 2><<<dim3(8, 64, 1), 256, 0, stream>>>(Xq, WqT, bq, Qh, nullptr, 1024, 1024, 1024, 0, 0);
  gemm_nt<M_KPROJ, 2, 2><<<dim3(8, 64, 1), 256, 0, stream>>>(Xk, WkT, bk, Kh, nullptr, 1024, 1024, 1024, 0, 0);
  gemm_nt<M_VPROJ, 2, 2><<<dim3(8, 64, 1), 256, 0, stream>>>(Xv, WvT, bv, VhT, nullptr, 1024, 1024, 1024, 0, 0);
  // 4) fused attention: scores + softmax (probs -> d_out, fp32) + P·V -> Ctx
  attn_fused_kernel<<<1024, 256, 0, stream>>>(Qh, Kh, VhT, mask, attnF, Ctx);
  // 5) output projection
  gemm_nt<M_OPROJ, 2, 2><<<dim3(8, 64, 1), 256, 0, stream>>>(Ctx, WoT, bo, tmp1, nullptr, 1024, 1024, 1024, 0, 0);
  // 6) double LayerNorm (MHA-internal eps 1e-8, encoder eps 1e-6)
  ln_mha_kernel<<<8192, 256, 0, stream>>>(tmp1, query, ln_mha_g, ln_mha_b, ln_attn_g, ln_attn_b, AttnOut, AttnOutBf);
  // 7) FFN
  gemm_nt<M_FFN1, 2, 2><<<dim3(32, 64, 1), 256, 0, stream>>>(AttnOutBf, W1T, b1, Hid, nullptr, 1024, 1024, 1024, 0, 0);
  gemm_nt<M_FFN2, 2, 2><<<dim3(8, 64, 1), 256, 0, stream>>>(Hid, W2T, b2, tmp1, nullptr, 4096, 4096, 4096, 0, 0);
  // 8) final LayerNorm -> d_out
  ln_final_kernel<<<8192, 256, 0, stream>>>(tmp1, AttnOut, ln_ffn_g, ln_ffn_b, outF);
}